// Round 2
// baseline (700.915 us; speedup 1.0000x reference)
//
#include <hip/hip_runtime.h>

// Problem constants
#define K_CODES 512
#define DIM 80
#define SEQ 4096
#define BATCH 32
#define NVEC (BATCH * SEQ)          // 131072 vectors
#define NELEM ((size_t)NVEC * DIM)  // 10485760 quantized elements
#define VPB 128                     // vectors per block
#define KHALF 256                   // codes per thread (k-split by 2)

// ws layout: [0..511] int hist | +2048: float sqsum | +4096: float wsq[512]

__global__ void vq_wsq(const float* __restrict__ weight, float* __restrict__ wsq) {
    int k = threadIdx.x;  // 512 threads
    const float* w = weight + (size_t)k * DIM;
    float s = 0.f;
#pragma unroll
    for (int c = 0; c < DIM; ++c) s = fmaf(w[c], w[c], s);
    wsq[k] = s;
}

__global__ __launch_bounds__(256, 4) void vq_main(
    const float* __restrict__ x, const float* __restrict__ weight,
    const float* __restrict__ wsq, float* __restrict__ out,
    int* __restrict__ ghist, float* __restrict__ gsq)
{
    __shared__ float sd[VPB];
    __shared__ int   sk[VPB];
    __shared__ int   lhist[K_CODES];
    __shared__ float lsum[4];
    const int tid = threadIdx.x;
    for (int i = tid; i < K_CODES; i += 256) lhist[i] = 0;

    const int vloc  = tid & (VPB - 1);
    const int khalf = tid >> 7;              // 0: codes 0-255, 1: codes 256-511
    const int v = blockIdx.x * VPB + vloc;   // vector id
    const int b = v >> 12;
    const int l = v & 4095;
    const float* xp = x + ((size_t)b * DIM) * SEQ + l;

    // this thread's 80-dim vector, register-resident (128-VGPR budget)
    float xv[DIM];
#pragma unroll
    for (int c = 0; c < DIM; ++c) xv[c] = xp[(size_t)c * SEQ];

    const int kbase = khalf * KHALF;
    float bestd = 3.4028235e38f;
    int bestk = kbase;

    for (int k = kbase; k < kbase + KHALF; k += 4) {
        const float* w0 = weight + (size_t)k * DIM;  // wave-uniform -> s_load
        float d0 = 0.f, d1 = 0.f, d2 = 0.f, d3 = 0.f;
#pragma unroll
        for (int c = 0; c < DIM; c += 4) {
            float4 a  = *(const float4*)(w0 + c);
            float4 bq = *(const float4*)(w0 + DIM + c);
            float4 cq = *(const float4*)(w0 + 2 * DIM + c);
            float4 dq = *(const float4*)(w0 + 3 * DIM + c);
            d0 = fmaf(xv[c + 0], a.x, d0);
            d0 = fmaf(xv[c + 1], a.y, d0);
            d0 = fmaf(xv[c + 2], a.z, d0);
            d0 = fmaf(xv[c + 3], a.w, d0);
            d1 = fmaf(xv[c + 0], bq.x, d1);
            d1 = fmaf(xv[c + 1], bq.y, d1);
            d1 = fmaf(xv[c + 2], bq.z, d1);
            d1 = fmaf(xv[c + 3], bq.w, d1);
            d2 = fmaf(xv[c + 0], cq.x, d2);
            d2 = fmaf(xv[c + 1], cq.y, d2);
            d2 = fmaf(xv[c + 2], cq.z, d2);
            d2 = fmaf(xv[c + 3], cq.w, d2);
            d3 = fmaf(xv[c + 0], dq.x, d3);
            d3 = fmaf(xv[c + 1], dq.y, d3);
            d3 = fmaf(xv[c + 2], dq.z, d3);
            d3 = fmaf(xv[c + 3], dq.w, d3);
        }
        float q0 = fmaf(-2.f, d0, wsq[k + 0]);
        float q1 = fmaf(-2.f, d1, wsq[k + 1]);
        float q2 = fmaf(-2.f, d2, wsq[k + 2]);
        float q3 = fmaf(-2.f, d3, wsq[k + 3]);
        if (q0 < bestd) { bestd = q0; bestk = k + 0; }
        if (q1 < bestd) { bestd = q1; bestk = k + 1; }
        if (q2 < bestd) { bestd = q2; bestk = k + 2; }
        if (q3 < bestd) { bestd = q3; bestk = k + 3; }
    }

    // exchange upper-half results; lower half combines (tie -> lower index wins)
    if (khalf) { sd[vloc] = bestd; sk[vloc] = bestk; }
    __syncthreads();   // also orders lhist init before atomics below

    float sq = 0.f;
    if (!khalf) {
        float d1 = sd[vloc]; int k1 = sk[vloc];
        if (d1 < bestd) { bestd = d1; bestk = k1; }

        atomicAdd(&lhist[bestk], 1);

        const float* wb = weight + (size_t)bestk * DIM;  // divergent gather, L2-hit
        float* op = out + 1 + ((size_t)b * DIM) * SEQ + l;
#pragma unroll
        for (int c = 0; c < DIM; c += 4) {
            float4 wv = *(const float4*)(wb + c);
            float e0 = wv.x - xv[c + 0];
            float e1 = wv.y - xv[c + 1];
            float e2 = wv.z - xv[c + 2];
            float e3 = wv.w - xv[c + 3];
            sq = fmaf(e0, e0, sq);
            sq = fmaf(e1, e1, sq);
            sq = fmaf(e2, e2, sq);
            sq = fmaf(e3, e3, sq);
            op[(size_t)(c + 0) * SEQ] = wv.x;
            op[(size_t)(c + 1) * SEQ] = wv.y;
            op[(size_t)(c + 2) * SEQ] = wv.z;
            op[(size_t)(c + 3) * SEQ] = wv.w;
        }
    }

    // block loss reduction (upper-half threads contribute 0)
#pragma unroll
    for (int off = 32; off; off >>= 1) sq += __shfl_down(sq, off, 64);
    if ((tid & 63) == 0) lsum[tid >> 6] = sq;
    __syncthreads();   // also orders lhist atomics before flush
    if (tid == 0) {
        float s = lsum[0] + lsum[1] + lsum[2] + lsum[3];
        atomicAdd(gsq, s);
    }

    for (int i = tid; i < K_CODES; i += 256) {
        int cnt = lhist[i];
        if (cnt) atomicAdd(&ghist[i], cnt);
    }
}

__global__ void vq_finalize(const int* __restrict__ hist,
                            const float* __restrict__ gsq,
                            float* __restrict__ out, int out_last)
{
    __shared__ float part[8];
    int t = threadIdx.x;  // 512 threads
    float p = (float)hist[t] * (1.0f / (float)NVEC);
    float term = p * logf(p + 1e-10f);
#pragma unroll
    for (int off = 32; off; off >>= 1) term += __shfl_down(term, off, 64);
    if ((t & 63) == 0) part[t >> 6] = term;
    __syncthreads();
    if (t == 0) {
        float s = 0.f;
#pragma unroll
        for (int i = 0; i < 8; ++i) s += part[i];
        out[out_last] = expf(-s);
        out[0] = 1.25f * gsq[0] / (float)NELEM;
    }
}

extern "C" void kernel_launch(void* const* d_in, const int* in_sizes, int n_in,
                              void* d_out, int out_size, void* d_ws, size_t ws_size,
                              hipStream_t stream) {
    const float* x = (const float*)d_in[0];
    const float* weight = (const float*)d_in[1];
    float* out = (float*)d_out;

    int* ghist = (int*)d_ws;
    float* gsq = (float*)((char*)d_ws + 2048);
    float* wsq = (float*)((char*)d_ws + 4096);

    hipMemsetAsync(d_ws, 0, 2052, stream);

    vq_wsq<<<1, K_CODES, 0, stream>>>(weight, wsq);
    vq_main<<<NVEC / VPB, 256, 0, stream>>>(x, weight, wsq, out, ghist, gsq);
    vq_finalize<<<1, K_CODES, 0, stream>>>(ghist, gsq, out, out_size - 1);
}

// Round 3
// 353.087 us; speedup vs baseline: 1.9851x; 1.9851x over previous
//
#include <hip/hip_runtime.h>

// Problem constants
#define K_CODES 512
#define DIM 80
#define SEQ 4096
#define BATCH 32
#define NVEC (BATCH * SEQ)          // 131072 vectors
#define NELEM ((size_t)NVEC * DIM)  // 10485760 quantized elements

// ws layout: [0..511] int hist | +2048: float sqsum | +4096: float wsq[512]

__global__ void vq_wsq(const float* __restrict__ weight, float* __restrict__ wsq) {
    int k = threadIdx.x;  // 512 threads
    const float* w = weight + (size_t)k * DIM;
    float s = 0.f;
#pragma unroll
    for (int c = 0; c < DIM; ++c) s = fmaf(w[c], w[c], s);
    wsq[k] = s;
}

__global__ __launch_bounds__(256, 4) void vq_main(
    const float* __restrict__ x, const float* __restrict__ weight,
    const float* __restrict__ wsq, float* __restrict__ out,
    int* __restrict__ ghist, float* __restrict__ gsq)
{
    __shared__ int lhist[K_CODES];
    __shared__ float lsum[4];
    const int tid = threadIdx.x;
    for (int i = tid; i < K_CODES; i += 256) lhist[i] = 0;
    __syncthreads();

    const int t = blockIdx.x * 256 + tid;   // vector id, grid exactly covers NVEC
    const int b = t >> 12;                  // / 4096
    const int l = t & 4095;
    const float* xp = x + ((size_t)b * DIM) * SEQ + l;

    // Load this thread's 80-dim vector, then PIN it in VGPRs. Without the
    // pin, the compiler sinks these loads into the k-loop (R1/R2: VGPR=52/64,
    // L1-reload-bound, VALUBusy<=40%). The "+v" asm forces each element to
    // materialize in a VGPR; later uses must read that register.
    float xv[DIM];
#pragma unroll
    for (int c = 0; c < DIM; ++c) xv[c] = xp[(size_t)c * SEQ];
#pragma unroll
    for (int c = 0; c < DIM; ++c) asm volatile("" : "+v"(xv[c]));

    float bestd = 3.4028235e38f;
    int bestk = 0;

    for (int k = 0; k < K_CODES; k += 4) {
        const float* w0 = weight + (size_t)k * DIM;  // wave-uniform -> s_load
        float d0 = 0.f, d1 = 0.f, d2 = 0.f, d3 = 0.f;
#pragma unroll
        for (int c = 0; c < DIM; c += 4) {
            float4 a  = *(const float4*)(w0 + c);
            float4 bq = *(const float4*)(w0 + DIM + c);
            float4 cq = *(const float4*)(w0 + 2 * DIM + c);
            float4 dq = *(const float4*)(w0 + 3 * DIM + c);
            d0 = fmaf(xv[c + 0], a.x, d0);
            d0 = fmaf(xv[c + 1], a.y, d0);
            d0 = fmaf(xv[c + 2], a.z, d0);
            d0 = fmaf(xv[c + 3], a.w, d0);
            d1 = fmaf(xv[c + 0], bq.x, d1);
            d1 = fmaf(xv[c + 1], bq.y, d1);
            d1 = fmaf(xv[c + 2], bq.z, d1);
            d1 = fmaf(xv[c + 3], bq.w, d1);
            d2 = fmaf(xv[c + 0], cq.x, d2);
            d2 = fmaf(xv[c + 1], cq.y, d2);
            d2 = fmaf(xv[c + 2], cq.z, d2);
            d2 = fmaf(xv[c + 3], cq.w, d2);
            d3 = fmaf(xv[c + 0], dq.x, d3);
            d3 = fmaf(xv[c + 1], dq.y, d3);
            d3 = fmaf(xv[c + 2], dq.z, d3);
            d3 = fmaf(xv[c + 3], dq.w, d3);
        }
        float q0 = fmaf(-2.f, d0, wsq[k + 0]);
        float q1 = fmaf(-2.f, d1, wsq[k + 1]);
        float q2 = fmaf(-2.f, d2, wsq[k + 2]);
        float q3 = fmaf(-2.f, d3, wsq[k + 3]);
        if (q0 < bestd) { bestd = q0; bestk = k + 0; }
        if (q1 < bestd) { bestd = q1; bestk = k + 1; }
        if (q2 < bestd) { bestd = q2; bestk = k + 2; }
        if (q3 < bestd) { bestd = q3; bestk = k + 3; }
    }

    // histogram (block-local)
    atomicAdd(&lhist[bestk], 1);

    // quantized output + squared-error accumulation
    const float* wb = weight + (size_t)bestk * DIM;  // divergent gather, L2-hit
    float* op = out + 1 + ((size_t)b * DIM) * SEQ + l;
    float sq = 0.f;
#pragma unroll
    for (int c = 0; c < DIM; c += 4) {
        float4 wv = *(const float4*)(wb + c);
        float e0 = wv.x - xv[c + 0];
        float e1 = wv.y - xv[c + 1];
        float e2 = wv.z - xv[c + 2];
        float e3 = wv.w - xv[c + 3];
        sq = fmaf(e0, e0, sq);
        sq = fmaf(e1, e1, sq);
        sq = fmaf(e2, e2, sq);
        sq = fmaf(e3, e3, sq);
        op[(size_t)(c + 0) * SEQ] = wv.x;
        op[(size_t)(c + 1) * SEQ] = wv.y;
        op[(size_t)(c + 2) * SEQ] = wv.z;
        op[(size_t)(c + 3) * SEQ] = wv.w;
    }

    // block loss reduction
#pragma unroll
    for (int off = 32; off; off >>= 1) sq += __shfl_down(sq, off, 64);
    if ((tid & 63) == 0) lsum[tid >> 6] = sq;
    __syncthreads();
    if (tid == 0) {
        float s = lsum[0] + lsum[1] + lsum[2] + lsum[3];
        atomicAdd(gsq, s);
    }

    // flush histogram
    for (int i = tid; i < K_CODES; i += 256) {
        int cnt = lhist[i];
        if (cnt) atomicAdd(&ghist[i], cnt);
    }
}

__global__ void vq_finalize(const int* __restrict__ hist,
                            const float* __restrict__ gsq,
                            float* __restrict__ out, int out_last)
{
    __shared__ float part[8];
    int t = threadIdx.x;  // 512 threads
    float p = (float)hist[t] * (1.0f / (float)NVEC);
    float term = p * logf(p + 1e-10f);
#pragma unroll
    for (int off = 32; off; off >>= 1) term += __shfl_down(term, off, 64);
    if ((t & 63) == 0) part[t >> 6] = term;
    __syncthreads();
    if (t == 0) {
        float s = 0.f;
#pragma unroll
        for (int i = 0; i < 8; ++i) s += part[i];
        out[out_last] = expf(-s);
        out[0] = 1.25f * gsq[0] / (float)NELEM;
    }
}

extern "C" void kernel_launch(void* const* d_in, const int* in_sizes, int n_in,
                              void* d_out, int out_size, void* d_ws, size_t ws_size,
                              hipStream_t stream) {
    const float* x = (const float*)d_in[0];
    const float* weight = (const float*)d_in[1];
    float* out = (float*)d_out;

    int* ghist = (int*)d_ws;
    float* gsq = (float*)((char*)d_ws + 2048);
    float* wsq = (float*)((char*)d_ws + 4096);

    hipMemsetAsync(d_ws, 0, 2052, stream);

    vq_wsq<<<1, K_CODES, 0, stream>>>(weight, wsq);
    vq_main<<<NVEC / 256, 256, 0, stream>>>(x, weight, wsq, out, ghist, gsq);
    vq_finalize<<<1, K_CODES, 0, stream>>>(ghist, gsq, out, out_size - 1);
}